// Round 4
// baseline (57.791 us; speedup 1.0000x reference)
//
#include <hip/hip_runtime.h>
#include <hip/hip_bf16.h>
#include <stdint.h>

// x [8,2048,768] f32, prototypes [1024,768] f32
// out = distances [16384,1024] f32 ++ prototypes copy [1024,768] f32
#define M_ROWS 16384
#define N_COLS 1024
#define K_DIM  768
#define NKT    12   // K_DIM / 64

typedef __attribute__((ext_vector_type(8))) short bf16x8;
typedef __attribute__((ext_vector_type(4))) float f32x4;

__device__ __forceinline__ void async_copy16(void* lds, const void* g) {
  __builtin_amdgcn_global_load_lds(
      (const __attribute__((address_space(1))) unsigned int*)g,
      (__attribute__((address_space(3))) unsigned int*)lds,
      16, 0, 0);
}

__device__ __forceinline__ short b16(float f) {
  __hip_bfloat16 h = __float2bfloat16(f);
  return *reinterpret_cast<short*>(&h);
}

__device__ __forceinline__ unsigned short f2bf(float f) {
  __hip_bfloat16 h = __float2bfloat16(f);
  return *reinterpret_cast<unsigned short*>(&h);
}

// wave-per-row prep for PROTOTYPES only: f32->bf16, ||p||^2, f32 copy to out.
__global__ void prep_rows(const float* __restrict__ src,
                          unsigned short* __restrict__ dstb,
                          float* __restrict__ sq,
                          float* __restrict__ copy_out) {
  const int wid = threadIdx.x >> 6;
  const int lane = threadIdx.x & 63;
  const int row = blockIdx.x * 4 + wid;
  const float4* r = (const float4*)(src + (size_t)row * K_DIM);
  ushort4* rb = (ushort4*)(dstb + (size_t)row * K_DIM);
  float4* cp = (float4*)(copy_out + (size_t)row * K_DIM);
  float acc = 0.f;
#pragma unroll
  for (int i = 0; i < 3; ++i) {
    float4 v = r[i * 64 + lane];
    acc += v.x * v.x + v.y * v.y + v.z * v.z + v.w * v.w;
    ushort4 u;
    u.x = f2bf(v.x); u.y = f2bf(v.y); u.z = f2bf(v.z); u.w = f2bf(v.w);
    rb[i * 64 + lane] = u;
    cp[i * 64 + lane] = v;
  }
#pragma unroll
  for (int off = 32; off; off >>= 1) acc += __shfl_down(acc, off);
  if (lane == 0) sq[row] = acc;
}

// LDS tile: [256 rows][64 bf16] = 128 B rows, 8 x 16B slots.
// Stored slot = logical slot ^ (row & 7).
__device__ __forceinline__ bf16x8 ldsfrag(const char* tile, int row, int slot) {
  return *(const bf16x8*)(tile + row * 128 + (((slot ^ (row & 7)) << 4)));
}

// 256x256 tile, BK=64, 512 thr = 8 waves (2M x 4N), 128x64 out per wave.
// A staged f32->bf16 in-kernel (reg path, ds_write swizzled) with fused
// ||x||^2 accumulation; B staged via global_load_lds (pre-swizzled source).
// 4 phases/K-tile; all next-tile loads issued in phases 0-1 (A regs + B h0)
// and phase 1 (B h1); A cvt+ds_write in phases 2-3; full drain only at the
// K-tile boundary (__syncthreads), by which point loads are ~3 phases old.
__global__ __launch_bounds__(512, 2) void dist_gemm(
    const float* __restrict__ x,
    const __hip_bfloat16* __restrict__ pb,
    const float* __restrict__ psq,
    float* __restrict__ out) {
  __shared__ char lds[2][2][32768];  // [buf][A/B][256x64 bf16] = 128 KB
  __shared__ float xsq_s[256];

  // XCD swizzle: 256 blocks; xcd owns bm in [xcd*8, xcd*8+8), all 4 bn.
  const int flat = blockIdx.x;
  const int xcd = flat & 7;
  const int local = flat >> 3;
  const int bm = xcd * 8 + (local >> 2);  // 0..63
  const int bn = local & 3;               // 0..3

  const int tid = threadIdx.x;
  const int wave = tid >> 6;
  const int lane = tid & 63;
  const int wm = wave >> 2;   // 0..1
  const int wn = wave & 3;    // 0..3
  const int rl = lane & 15;
  const int kq = lane >> 4;

  f32x4 acc[8][4] = {};
  bf16x8 af[4][2], bfr[4][2];
  float4 av0[4], av1[4];
  float ssq[4] = {0.f, 0.f, 0.f, 0.f};

  const float* Ax = x + (size_t)(bm * 256) * K_DIM;
  const __hip_bfloat16* Bbase = pb + (size_t)(bn * 256) * K_DIM;

  const int rih = tid >> 3;                      // 0..63
  const int slot = tid & 7;                      // 0..7
  const int g8 = ((slot ^ (rih & 7))) * 8;       // B pre-swizzled src offset

  // ---- A: global f32 -> regs (4 row-slices of 8 f32 per thread) ----
#define ALOAD(ktile)                                                        \
  do {                                                                      \
    _Pragma("unroll") for (int g = 0; g < 4; ++g) {                         \
      const float* ap =                                                     \
          Ax + (size_t)(g * 64 + rih) * K_DIM + (ktile) * 64 + slot * 8;    \
      av0[g] = *(const float4*)ap;                                          \
      av1[g] = *(const float4*)(ap + 4);                                    \
    }                                                                       \
  } while (0)

  // cvt + swizzled ds_write + fused ssq accumulation
#define AWRITE(tile, g)                                                     \
  do {                                                                      \
    const int row_ = (g) * 64 + rih;                                        \
    bf16x8 v_;                                                              \
    v_[0] = b16(av0[g].x); v_[1] = b16(av0[g].y);                           \
    v_[2] = b16(av0[g].z); v_[3] = b16(av0[g].w);                           \
    v_[4] = b16(av1[g].x); v_[5] = b16(av1[g].y);                           \
    v_[6] = b16(av1[g].z); v_[7] = b16(av1[g].w);                           \
    *(bf16x8*)((tile) + row_ * 128 + ((slot ^ (row_ & 7)) << 4)) = v_;      \
    ssq[g] += av0[g].x * av0[g].x + av0[g].y * av0[g].y +                   \
              av0[g].z * av0[g].z + av0[g].w * av0[g].w +                   \
              av1[g].x * av1[g].x + av1[g].y * av1[g].y +                   \
              av1[g].z * av1[g].z + av1[g].w * av1[g].w;                    \
  } while (0)

  // B: one half-tile (128 rows) via 2 x global_load_lds per thread
#define BSTAGE(tile, h, ktile)                                              \
  do {                                                                      \
    _Pragma("unroll") for (int c = 0; c < 2; ++c) {                         \
      async_copy16((tile) + (h) * 16384 + (c * 512 + tid) * 16,             \
                   Bbase + (size_t)((h) * 128 + c * 64 + rih) * K_DIM +     \
                       (ktile) * 64 + g8);                                  \
    }                                                                       \
  } while (0)

  // prologue: tile 0
  {
    char* A0 = &lds[0][0][0];
    char* B0 = &lds[0][1][0];
    BSTAGE(B0, 0, 0);
    BSTAGE(B0, 1, 0);
    ALOAD(0);
    AWRITE(A0, 0); AWRITE(A0, 1); AWRITE(A0, 2); AWRITE(A0, 3);
  }
  __syncthreads();

  for (int kt = 0; kt < NKT; ++kt) {
    const char* At = &lds[kt & 1][0][0];
    const char* Bt = &lds[kt & 1][1][0];
    char* An = &lds[(kt + 1) & 1][0][0];
    char* Bn = &lds[(kt + 1) & 1][1][0];
    const bool pf = (kt + 1 < NKT);

    // ---- phase 0: Q(mq=0,nq=0); issue next A reg-loads + B h0 ----
#pragma unroll
    for (int mi = 0; mi < 4; ++mi)
#pragma unroll
      for (int kk = 0; kk < 2; ++kk)
        af[mi][kk] = ldsfrag(At, wm * 128 + mi * 16 + rl, kk * 4 + kq);
#pragma unroll
    for (int ni = 0; ni < 2; ++ni)
#pragma unroll
      for (int kk = 0; kk < 2; ++kk)
        bfr[ni][kk] = ldsfrag(Bt, wn * 64 + ni * 16 + rl, kk * 4 + kq);
    if (pf) {
      BSTAGE(Bn, 0, kt + 1);
      ALOAD(kt + 1);
    }
    asm volatile("s_barrier" ::: "memory");
    __builtin_amdgcn_s_setprio(1);
#pragma unroll
    for (int mi = 0; mi < 4; ++mi)
#pragma unroll
      for (int ni = 0; ni < 2; ++ni)
#pragma unroll
        for (int kk = 0; kk < 2; ++kk)
          acc[mi][ni] = __builtin_amdgcn_mfma_f32_16x16x32_bf16(
              af[mi][kk], bfr[ni][kk], acc[mi][ni], 0, 0, 0);
    __builtin_amdgcn_s_setprio(0);
    asm volatile("s_barrier" ::: "memory");

    // ---- phase 1: Q(mq=0,nq=1); issue B h1 ----
#pragma unroll
    for (int ni = 2; ni < 4; ++ni)
#pragma unroll
      for (int kk = 0; kk < 2; ++kk)
        bfr[ni][kk] = ldsfrag(Bt, wn * 64 + ni * 16 + rl, kk * 4 + kq);
    if (pf) BSTAGE(Bn, 1, kt + 1);
    asm volatile("s_barrier" ::: "memory");
    __builtin_amdgcn_s_setprio(1);
#pragma unroll
    for (int mi = 0; mi < 4; ++mi)
#pragma unroll
      for (int ni = 0; ni < 2; ++ni)
#pragma unroll
        for (int kk = 0; kk < 2; ++kk)
          acc[mi][2 + ni] = __builtin_amdgcn_mfma_f32_16x16x32_bf16(
              af[mi][kk], bfr[2 + ni][kk], acc[mi][2 + ni], 0, 0, 0);
    __builtin_amdgcn_s_setprio(0);
    asm volatile("s_barrier" ::: "memory");

    // ---- phase 2: Q(mq=1,nq=0); cvt+write A halves 0,1 ----
#pragma unroll
    for (int mi = 0; mi < 4; ++mi)
#pragma unroll
      for (int kk = 0; kk < 2; ++kk)
        af[mi][kk] = ldsfrag(At, wm * 128 + 64 + mi * 16 + rl, kk * 4 + kq);
    if (pf) { AWRITE(An, 0); AWRITE(An, 1); }
    asm volatile("s_barrier" ::: "memory");
    __builtin_amdgcn_s_setprio(1);
#pragma unroll
    for (int mi = 0; mi < 4; ++mi)
#pragma unroll
      for (int ni = 0; ni < 2; ++ni)
#pragma unroll
        for (int kk = 0; kk < 2; ++kk)
          acc[4 + mi][ni] = __builtin_amdgcn_mfma_f32_16x16x32_bf16(
              af[mi][kk], bfr[ni][kk], acc[4 + mi][ni], 0, 0, 0);
    __builtin_amdgcn_s_setprio(0);
    asm volatile("s_barrier" ::: "memory");

    // ---- phase 3: Q(mq=1,nq=1); cvt+write A halves 2,3; boundary drain ----
    if (pf) { AWRITE(An, 2); AWRITE(An, 3); }
    asm volatile("s_barrier" ::: "memory");
    __builtin_amdgcn_s_setprio(1);
#pragma unroll
    for (int mi = 0; mi < 4; ++mi)
#pragma unroll
      for (int ni = 0; ni < 2; ++ni)
#pragma unroll
        for (int kk = 0; kk < 2; ++kk)
          acc[4 + mi][2 + ni] = __builtin_amdgcn_mfma_f32_16x16x32_bf16(
              af[mi][kk], bfr[2 + ni][kk], acc[4 + mi][2 + ni], 0, 0, 0);
    __builtin_amdgcn_s_setprio(0);
    __syncthreads();  // vmcnt(0)+lgkmcnt(0)+barrier: buf[(kt+1)&1] complete
  }
#undef ALOAD
#undef AWRITE
#undef BSTAGE

  // ---- xsq: reduce the fused per-thread row sums across the 8-lane group ----
#pragma unroll
  for (int g = 0; g < 4; ++g) {
#pragma unroll
    for (int m = 1; m < 8; m <<= 1) ssq[g] += __shfl_xor(ssq[g], m);
  }
  if (slot == 0) {
#pragma unroll
    for (int g = 0; g < 4; ++g) xsq_s[g * 64 + rih] = ssq[g];
  }
  __syncthreads();

  // epilogue: dist = xsq[row] + psq[col] - 2*acc
  // C/D layout: col = lane&15, row = (lane>>4)*4 + reg
  const int c0 = bn * 256 + wn * 64;
#pragma unroll
  for (int mf = 0; mf < 8; ++mf) {
#pragma unroll
    for (int nf = 0; nf < 4; ++nf) {
      const int col = c0 + nf * 16 + rl;
      const float ps = psq[col];
#pragma unroll
      for (int r = 0; r < 4; ++r) {
        const int rloc = wm * 128 + mf * 16 + kq * 4 + r;
        out[(size_t)(bm * 256 + rloc) * N_COLS + col] =
            xsq_s[rloc] + ps - 2.0f * acc[mf][nf][r];
      }
    }
  }
}

extern "C" void kernel_launch(void* const* d_in, const int* in_sizes, int n_in,
                              void* d_out, int out_size, void* d_ws, size_t ws_size,
                              hipStream_t stream) {
  const float* x = (const float*)d_in[0];
  const float* p = (const float*)d_in[1];
  float* out = (float*)d_out;
  char* ws = (char*)d_ws;

  float* psq = (float*)ws;                               // 4 KB
  unsigned short* pbu = (unsigned short*)(ws + 4096);    // 1.5 MB
  float* proto_out = out + (size_t)M_ROWS * N_COLS;

  prep_rows<<<N_COLS / 4, 256, 0, stream>>>(p, pbu, psq, proto_out);

  dist_gemm<<<256, 512, 0, stream>>>(x, (const __hip_bfloat16*)pbu,
                                     psq, out);
}

// Round 5
// 47.108 us; speedup vs baseline: 1.2268x; 1.2268x over previous
//
#include <hip/hip_runtime.h>
#include <hip/hip_bf16.h>
#include <stdint.h>

// x [8,2048,768] f32, prototypes [1024,768] f32
// out = distances [16384,1024] f32 ++ prototypes copy [1024,768] f32
#define M_ROWS 16384
#define N_COLS 1024
#define K_DIM  768
#define NKT    12   // K_DIM / 64

typedef __attribute__((ext_vector_type(8))) short bf16x8;
typedef __attribute__((ext_vector_type(4))) float f32x4;

__device__ __forceinline__ void async_copy16(void* lds, const void* g) {
  __builtin_amdgcn_global_load_lds(
      (const __attribute__((address_space(1))) unsigned int*)g,
      (__attribute__((address_space(3))) unsigned int*)lds,
      16, 0, 0);
}

__device__ __forceinline__ unsigned short f2bf(float f) {
  __hip_bfloat16 h = __float2bfloat16(f);
  return *reinterpret_cast<unsigned short*>(&h);
}

// Combined prep, one launch: blocks [0,4096) process x rows (4/block);
// blocks [4096,4352) process prototype rows (4/block) incl. f32 passthrough.
__global__ void prep_all(const float* __restrict__ x,
                         const float* __restrict__ p,
                         unsigned short* __restrict__ xb,
                         unsigned short* __restrict__ pbu,
                         float* __restrict__ xsq,
                         float* __restrict__ psq,
                         float* __restrict__ proto_out) {
  const int b = blockIdx.x;
  const int wid = threadIdx.x >> 6;
  const int lane = threadIdx.x & 63;
  const float* src;
  unsigned short* dst;
  float* sq;
  float* cp;
  int row;
  if (b < M_ROWS / 4) {
    row = b * 4 + wid;
    src = x; dst = xb; sq = xsq; cp = nullptr;
  } else {
    row = (b - M_ROWS / 4) * 4 + wid;
    src = p; dst = pbu; sq = psq; cp = proto_out;
  }
  const float4* r = (const float4*)(src + (size_t)row * K_DIM);
  ushort4* rb = (ushort4*)(dst + (size_t)row * K_DIM);
  float4* cpv = cp ? (float4*)(cp + (size_t)row * K_DIM) : nullptr;
  float acc = 0.f;
#pragma unroll
  for (int i = 0; i < 3; ++i) {
    float4 v = r[i * 64 + lane];
    acc += v.x * v.x + v.y * v.y + v.z * v.z + v.w * v.w;
    ushort4 u;
    u.x = f2bf(v.x); u.y = f2bf(v.y); u.z = f2bf(v.z); u.w = f2bf(v.w);
    rb[i * 64 + lane] = u;
    if (cpv) cpv[i * 64 + lane] = v;
  }
#pragma unroll
  for (int off = 32; off; off >>= 1) acc += __shfl_down(acc, off);
  if (lane == 0) sq[row] = acc;
}

// LDS tile: [128 rows][64 bf16] = 128 B rows, 8 x 16B slots.
// Stored slot = logical slot ^ (row & 7); source pre-swizzled (rule #21).
__device__ __forceinline__ bf16x8 ldsfrag(const char* tile, int row, int slot) {
  return *(const bf16x8*)(tile + row * 128 + (((slot ^ (row & 7)) << 4)));
}

// 128x128 tile, BK=64, 256 thr = 4 waves (2x2), 64x64 out per wave.
// T3 minimum-2-phase: STAGE(next) issued first, ds_read+MFMA cover the
// latency, ONE vmcnt(0)+barrier per K-tile. 64 KB LDS -> 2 blocks/CU
// resident; grid=1024 (4 blocks/CU) pipelines prologue/epilogue across
// blocks. Bijective XCD swizzle: each XCD owns 16 contiguous bm panels.
__global__ __launch_bounds__(256, 2) void dist_gemm(
    const __hip_bfloat16* __restrict__ xb,
    const __hip_bfloat16* __restrict__ pb,
    const float* __restrict__ xsq,
    const float* __restrict__ psq,
    float* __restrict__ out) {
  __shared__ char lds[2][2][16384];  // [buf][A|B][128x64 bf16] = 64 KB

  const int flat = blockIdx.x;       // 1024 blocks = 128 bm x 8 bn
  const int xcd = flat & 7;
  const int local = flat >> 3;       // 0..127
  const int bm = xcd * 16 + (local >> 3);  // 0..127
  const int bn = local & 7;                // 0..7

  const int tid = threadIdx.x;
  const int wave = tid >> 6;
  const int lane = tid & 63;
  const int wm = wave >> 1;   // 0..1
  const int wn = wave & 1;    // 0..1
  const int rl = lane & 15;
  const int kq = lane >> 4;   // 0..3

  f32x4 acc[4][4] = {};
  bf16x8 af[4][2], bfr[4][2];

  const __hip_bfloat16* Abase = xb + (size_t)(bm * 128) * K_DIM;
  const __hip_bfloat16* Bbase = pb + (size_t)(bn * 128) * K_DIM;

  // staging: 16 KB per operand tile = 1024 x 16B chunks; thread t, chunk c:
  // idx = c*256+t -> row = idx>>3, stored slot = t&7; source pre-swizzled.
  int gofs[4];
#pragma unroll
  for (int c = 0; c < 4; ++c) {
    const int row = c * 32 + (tid >> 3);
    const int g = (tid & 7) ^ (row & 7);
    gofs[c] = row * K_DIM + g * 8;  // elements
  }

#define STAGE(buf, ktile)                                                   \
  do {                                                                      \
    _Pragma("unroll") for (int c = 0; c < 4; ++c) {                         \
      const int lofs = (c * 256 + tid) * 16;                                \
      async_copy16(&lds[buf][0][0] + lofs, Abase + gofs[c] + (ktile) * 64); \
      async_copy16(&lds[buf][1][0] + lofs, Bbase + gofs[c] + (ktile) * 64); \
    }                                                                       \
  } while (0)

  // prologue
  STAGE(0, 0);
  asm volatile("s_waitcnt vmcnt(0)" ::: "memory");
  asm volatile("s_barrier" ::: "memory");

  for (int kt = 0; kt < NKT; ++kt) {
    const int cur = kt & 1;
    if (kt + 1 < NKT) STAGE(cur ^ 1, kt + 1);  // issue next-tile loads FIRST

    const char* At = &lds[cur][0][0];
    const char* Bt = &lds[cur][1][0];
#pragma unroll
    for (int mi = 0; mi < 4; ++mi)
#pragma unroll
      for (int kk = 0; kk < 2; ++kk)
        af[mi][kk] = ldsfrag(At, wm * 64 + mi * 16 + rl, kk * 4 + kq);
#pragma unroll
    for (int ni = 0; ni < 4; ++ni)
#pragma unroll
      for (int kk = 0; kk < 2; ++kk)
        bfr[ni][kk] = ldsfrag(Bt, wn * 64 + ni * 16 + rl, kk * 4 + kq);

    __builtin_amdgcn_s_setprio(1);
#pragma unroll
    for (int mi = 0; mi < 4; ++mi)
#pragma unroll
      for (int ni = 0; ni < 4; ++ni)
#pragma unroll
        for (int kk = 0; kk < 2; ++kk)
          acc[mi][ni] = __builtin_amdgcn_mfma_f32_16x16x32_bf16(
              af[mi][kk], bfr[ni][kk], acc[mi][ni], 0, 0, 0);
    __builtin_amdgcn_s_setprio(0);

    // single per-tile sync: next buffer complete, this buffer's reads already
    // consumed by the MFMAs above (no WAR on re-stage after the barrier).
    asm volatile("s_waitcnt vmcnt(0)" ::: "memory");
    asm volatile("s_barrier" ::: "memory");
  }
#undef STAGE

  // epilogue: dist = xsq[row] + psq[col] - 2*acc
  // C/D layout: col = lane&15, row = (lane>>4)*4 + reg
  const int c0 = bn * 128 + wn * 64;
  const int r0 = bm * 128 + wm * 64;
#pragma unroll
  for (int mi = 0; mi < 4; ++mi) {
#pragma unroll
    for (int ni = 0; ni < 4; ++ni) {
      const int col = c0 + ni * 16 + rl;
      const float ps = psq[col];
#pragma unroll
      for (int r = 0; r < 4; ++r) {
        const int row = r0 + mi * 16 + kq * 4 + r;
        out[(size_t)row * N_COLS + col] = xsq[row] + ps - 2.0f * acc[mi][ni][r];
      }
    }
  }
}

extern "C" void kernel_launch(void* const* d_in, const int* in_sizes, int n_in,
                              void* d_out, int out_size, void* d_ws, size_t ws_size,
                              hipStream_t stream) {
  const float* x = (const float*)d_in[0];
  const float* p = (const float*)d_in[1];
  float* out = (float*)d_out;
  char* ws = (char*)d_ws;

  float* xsq = (float*)ws;                                   // 64 KB
  float* psq = (float*)(ws + 65536);                         // 4 KB
  unsigned short* xb = (unsigned short*)(ws + 69632);        // 24 MB
  unsigned short* pbu = xb + (size_t)M_ROWS * K_DIM;         // 1.5 MB
  float* proto_out = out + (size_t)M_ROWS * N_COLS;

  prep_all<<<M_ROWS / 4 + N_COLS / 4, 256, 0, stream>>>(x, p, xb, pbu, xsq,
                                                        psq, proto_out);

  dist_gemm<<<1024, 256, 0, stream>>>((const __hip_bfloat16*)xb,
                                      (const __hip_bfloat16*)pbu,
                                      xsq, psq, out);
}